// Round 7
// baseline (191.010 us; speedup 1.0000x reference)
//
#include <hip/hip_runtime.h>

#define HEADS 8
#define DH 64
#define CO 3
#define E 192
#define NSEQ 2048
#define BATCH 2
#define CIN 256
#define DINNER 512
#define NTOK 4096
#define BHTOT 16

typedef __attribute__((ext_vector_type(8))) short bf16x8;
typedef __attribute__((ext_vector_type(4))) short bf16x4;
typedef __attribute__((ext_vector_type(4))) float f32x4;

static __device__ inline short f2bf(float f) {
  union { float f; unsigned u; } v; v.f = f;
  unsigned r = (v.u + 0x7FFFu + ((v.u >> 16) & 1u)) >> 16;  // RNE
  return (short)r;
}

static __device__ inline void load_lds16(const short* g, short* l) {
  __builtin_amdgcn_global_load_lds(
      (const __attribute__((address_space(1))) void*)g,
      (__attribute__((address_space(3))) void*)l, 16, 0, 0);
}

// Frag-tile packing: a 16(row)x32(k) bf16 MFMA operand tile = 512 shorts,
// element [row r][k = qd*8+j] at (qd*16 + r)*8 + j (consuming wave's lane order).
// Internal e-order: e = c*64 + d.

// ---------------------------------------------------------------- prep_w
__global__ __launch_bounds__(256) void prep_w(const float* __restrict__ Wq,
                                              const float* __restrict__ Wk,
                                              const float* __restrict__ Wv,
                                              const float* __restrict__ Wo,
                                              short* __restrict__ wqkvp,
                                              short* __restrict__ wop) {
  int idx = blockIdx.x * 256 + threadIdx.x;
  const float qscale = 0.07216878364870323f * 1.4426950408889634f;  // 192^-0.5 * log2(e)
  if (idx < 1536 * 256) {
    int o = idx >> 8, i = idx & 255;
    float v;
    if (o < 512) v = Wq[idx] * qscale;
    else if (o < 1024) v = Wk[idx - 512 * 256];
    else v = Wv[idx - 1024 * 256];
    int nt = o >> 4, ln = o & 15, ks = i >> 5, qd = (i >> 3) & 3, j = i & 7;
    wqkvp[((size_t)(nt * 8 + ks)) * 512 + (qd * 16 + ln) * 8 + j] = f2bf(v);
  } else {
    int j0 = idx - 1536 * 256;
    if (j0 < 256 * 512) {
      int o2 = j0 >> 9, i = j0 & 511;
      int nt = o2 >> 4, ln = o2 & 15, ks = i >> 5, qd = (i >> 3) & 3, j = i & 7;
      wop[((size_t)(nt * 16 + ks)) * 512 + (qd * 16 + ln) * 8 + j] = f2bf(Wo[j0]);
    }
  }
}

// ---------------------------------------------------------------- prep_x
__global__ __launch_bounds__(256) void prep_x(const float* __restrict__ x,
                                              short* __restrict__ xcp) {
  int idx = blockIdx.x * 256 + threadIdx.x;  // t*256 + i
  int t = idx >> 8, i = idx & 255;
  const float* p = x + (size_t)idx * 3;
  float a = p[0], b = p[1], c = p[2];
  int mt = t >> 4, ln = t & 15, ks = i >> 5, qd = (i >> 3) & 3, j = i & 7;
  size_t inner = (size_t)(qd * 16 + ln) * 8 + j;
  xcp[((size_t)(0 * 256 + mt) * 8 + ks) * 512 + inner] = f2bf(a);
  xcp[((size_t)(1 * 256 + mt) * 8 + ks) * 512 + inner] = f2bf(b);
  xcp[((size_t)(2 * 256 + mt) * 8 + ks) * 512 + inner] = f2bf(c);
}

// ---------------------------------------------------------------- qkv_gemm
__global__ __launch_bounds__(256, 3) void qkv_gemm(const short* __restrict__ xcp,
                                                   const short* __restrict__ wqkvp,
                                                   short* __restrict__ qp,
                                                   short* __restrict__ kp,
                                                   short* __restrict__ vp) {
  __shared__ __align__(16) short pool[17408];
  int c = blockIdx.z, ntb = blockIdx.x, mtb = blockIdx.y;
  int tid = threadIdx.x, wave = tid >> 6, lane = tid & 63;
  int ln = lane & 15, quad = lane >> 4;
  int wm = wave >> 1, wn = wave & 1;

  const short* gA = xcp + ((size_t)(c * 256 + mtb * 8) * 8) * 512;
  const short* gB = wqkvp + ((size_t)(ntb * 8) * 8) * 512;

  f32x4 acc[4][4] = {};
#pragma unroll
  for (int i = 0; i < 2; i++) {
    int q = tid + 256 * i, mf = q >> 6, l = q & 63;
    load_lds16(gA + (size_t)(mf * 8) * 512 + l * 8, pool + q * 8);
    load_lds16(gB + (size_t)(mf * 8) * 512 + l * 8, pool + 8192 + q * 8);
  }
  for (int ks = 0; ks < 8; ks++) {
    int b = ks & 1;
    __syncthreads();
    if (ks < 7) {
#pragma unroll
      for (int i = 0; i < 2; i++) {
        int q = tid + 256 * i, mf = q >> 6, l = q & 63;
        load_lds16(gA + (size_t)(mf * 8 + ks + 1) * 512 + l * 8, pool + (b ^ 1) * 4096 + q * 8);
        load_lds16(gB + (size_t)(mf * 8 + ks + 1) * 512 + l * 8, pool + 8192 + (b ^ 1) * 4096 + q * 8);
      }
    }
    const short* As = pool + b * 4096;
    const short* Bs = pool + 8192 + b * 4096;
    bf16x8 af[4], bfr[4];
#pragma unroll
    for (int i = 0; i < 4; i++) af[i] = *(const bf16x8*)&As[(wm * 4 + i) * 512 + lane * 8];
#pragma unroll
    for (int j = 0; j < 4; j++) bfr[j] = *(const bf16x8*)&Bs[(wn * 4 + j) * 512 + lane * 8];
#pragma unroll
    for (int i = 0; i < 4; i++)
#pragma unroll
      for (int j = 0; j < 4; j++)
        acc[i][j] = __builtin_amdgcn_mfma_f32_16x16x32_bf16(af[i], bfr[j], acc[i][j], 0, 0, 0);
  }

  int mat = ntb >> 2;
  int b0 = mtb >> 4;
  if (mat < 2) {
    __syncthreads();
    short* tp = pool;  // [128][136]
#pragma unroll
    for (int i = 0; i < 4; i++)
#pragma unroll
      for (int j = 0; j < 4; j++)
#pragma unroll
        for (int jj = 0; jj < 4; jj++)
          tp[(wm * 64 + i * 16 + quad * 4 + jj) * 136 + wn * 64 + j * 16 + ln] =
              f2bf(acc[i][j][jj]);
    __syncthreads();
    short* dst = (mat == 0) ? qp : kp;
    int h0 = (ntb & 3) * 2;
#pragma unroll
    for (int rep = 0; rep < 8; rep++) {
      int gi = rep * 256 + tid;
      int l2 = gi & 15, qd = (gi >> 4) & 3, nf2 = (gi >> 6) & 3,
          esp = (gi >> 8) & 1, hh = (gi >> 9) & 1, kt2 = gi >> 10;
      int tl = kt2 * 64 + nf2 * 16 + l2;
      bf16x8 val = *(const bf16x8*)&tp[tl * 136 + hh * 64 + (esp * 4 + qd) * 8];
      int bhx = b0 * 8 + h0 + hh;
      int kt = (mtb * 2 + kt2) & 31;
      int es = c * 2 + esp;
      size_t off = (((size_t)((bhx * 32 + kt) * 24) + es * 4 + nf2) * 64 +
                    (size_t)(qd * 16 + l2)) * 8;
      *(bf16x8*)(dst + off) = val;
    }
  } else {
#pragma unroll
    for (int i = 0; i < 4; i++) {
      int kt = (mtb * 2 + wm) & 31;
      int ks2 = (i >> 1) & 1;
      int qd2 = (i * 2 + (quad >> 1)) & 3;
#pragma unroll
      for (int j = 0; j < 4; j++) {
        int o = ntb * 128 + wn * 64 + j * 16 + ln;
        int oo = o & 511, h = oo >> 6, d = oo & 63;
        int ef = c * 4 + (d >> 4), l2v = d & 15;
        int bhx = b0 * 8 + h;
        size_t off = ((size_t)((bhx * 32 + kt) * 24 + ks2 * 12 + ef)) * 512 +
                     (qd2 * 16 + l2v) * 8 + (quad & 1) * 4;
        bf16x4 val = { f2bf(acc[i][j][0]), f2bf(acc[i][j][1]),
                       f2bf(acc[i][j][2]), f2bf(acc[i][j][3]) };
        *(bf16x4*)(vp + off) = val;
      }
    }
  }
}

// ---------------------------------------------------------------- attn
// Split-K(2) flash attention, R5-proven structure (no online max; exp2
// softmax, log2e folded into Q). Grid (32 pairs, 16 qt); block = 4 waves x
// 32 q-rows (R=2); LDS 67.6KB -> 2 blocks/CU (register ceiling anyway).
__global__ __launch_bounds__(256, 2) void attn(const short* __restrict__ qp,
                                               const short* __restrict__ kp,
                                               const short* __restrict__ vp,
                                               short* __restrict__ opart,
                                               float* __restrict__ lpart) {
  __shared__ __align__(16) short pool[33792];  // K 12288 | V 12288 | P [8][16][72]
  int pair = blockIdx.x, qt = blockIdx.y;
  int bh = pair & 15, kh = pair >> 4;
  int tid = threadIdx.x, wave = tid >> 6, lane = tid & 63;
  int ln = lane & 15, quad = lane >> 4;
  short* Kl = pool;
  short* Vl = pool + 12288;
  short* Pl = pool + 24576;

  bf16x8 qf[2][6];
#pragma unroll
  for (int rg = 0; rg < 2; rg++) {
    int fi = wave * 2 + rg;  // 16-row frag 0..7 within the 128-row q-tile
    const short* qb = qp +
        ((size_t)(bh * 32 + qt * 2 + (fi >> 2)) * 24 + (fi & 3)) * 512 + lane * 8;
#pragma unroll
    for (int es = 0; es < 6; es++) qf[rg][es] = *(const bf16x8*)(qb + es * 2048);
  }

  float l_r[2][4] = {};
  f32x4 acc[2][12] = {};
  const short* gKb = kp + (size_t)(bh * 32 + kh * 16) * 12288;
  const short* gVb = vp + (size_t)(bh * 32 + kh * 16) * 12288;

  for (int kt = 0; kt < 16; kt++) {
    const short* gK = gKb + (size_t)kt * 12288;
    const short* gV = gVb + (size_t)kt * 12288;
#pragma unroll
    for (int i = 0; i < 6; i++) {
      load_lds16(gK + (i * 256 + tid) * 8, Kl + (i * 256 + tid) * 8);
      load_lds16(gV + (i * 256 + tid) * 8, Vl + (i * 256 + tid) * 8);
    }
    __syncthreads();

    f32x4 s[2][4];
#pragma unroll
    for (int nf = 0; nf < 4; nf++) {
      f32x4 a0 = {}, a1 = {};
#pragma unroll
      for (int es = 0; es < 6; es++) {
        bf16x8 kf = *(const bf16x8*)&Kl[(es * 4 + nf) * 512 + lane * 8];
        a0 = __builtin_amdgcn_mfma_f32_16x16x32_bf16(qf[0][es], kf, a0, 0, 0, 0);
        a1 = __builtin_amdgcn_mfma_f32_16x16x32_bf16(qf[1][es], kf, a1, 0, 0, 0);
      }
      s[0][nf] = a0; s[1][nf] = a1;
    }

#pragma unroll
    for (int rg = 0; rg < 2; rg++)
#pragma unroll
      for (int jj = 0; jj < 4; jj++)
#pragma unroll
        for (int nf = 0; nf < 4; nf++) {
          float p = __builtin_amdgcn_exp2f(s[rg][nf][jj]);
          union { float f; unsigned u; } v; v.f = p;
          Pl[((wave * 2 + rg) * 16 + quad * 4 + jj) * 72 + nf * 16 + ln] =
              (short)((v.u + 0x8000u) >> 16);
          l_r[rg][jj] += p;  // unrounded: unbiased vs rounded-P sum
        }

    bf16x8 pa[2][2];
#pragma unroll
    for (int rg = 0; rg < 2; rg++) {
      const short* pb = &Pl[((wave * 2 + rg) * 16 + ln) * 72 + quad * 8];
      pa[rg][0] = *(const bf16x8*)pb;
      pa[rg][1] = *(const bf16x8*)(pb + 32);
    }
#pragma unroll
    for (int ef = 0; ef < 12; ef++) {
      bf16x8 v0 = *(const bf16x8*)&Vl[ef * 512 + lane * 8];
      bf16x8 v1 = *(const bf16x8*)&Vl[(12 + ef) * 512 + lane * 8];
#pragma unroll
      for (int rg = 0; rg < 2; rg++) {
        acc[rg][ef] = __builtin_amdgcn_mfma_f32_16x16x32_bf16(pa[rg][0], v0, acc[rg][ef], 0, 0, 0);
        acc[rg][ef] = __builtin_amdgcn_mfma_f32_16x16x32_bf16(pa[rg][1], v1, acc[rg][ef], 0, 0, 0);
      }
    }
    __syncthreads();
  }

#pragma unroll
  for (int rg = 0; rg < 2; rg++)
#pragma unroll
    for (int jj = 0; jj < 4; jj++)
#pragma unroll
      for (int off = 1; off < 16; off <<= 1)
        l_r[rg][jj] += __shfl_xor(l_r[rg][jj], off, 64);

  // epilogue: transpose (UNNORMALIZED) -> contiguous opart rows; store l
  short* tp = pool;  // [128][200] = 25600 <= 33792
#pragma unroll
  for (int rg = 0; rg < 2; rg++)
#pragma unroll
    for (int jj = 0; jj < 4; jj++) {
      int row = (wave * 2 + rg) * 16 + quad * 4 + jj;
#pragma unroll
      for (int ef = 0; ef < 12; ef++)
        tp[row * 200 + ef * 16 + ln] = f2bf(acc[rg][ef][jj]);
    }
  __syncthreads();
  const size_t obase = ((size_t)(kh * 16 + bh) * 2048 + qt * 128) * 192;
#pragma unroll
  for (int rep = 0; rep < 12; rep++) {
    int gi = rep * 256 + tid;           // 128 rows x 24 chunks
    int row = gi / 24, c8 = gi - row * 24;
    *(bf16x8*)(opart + obase + (size_t)row * 192 + c8 * 8) =
        *(const bf16x8*)&tp[row * 200 + c8 * 8];
  }
  int lb = (kh * 16 + bh) * 2048 + qt * 128;
  if (ln == 0) {
#pragma unroll
    for (int rg = 0; rg < 2; rg++)
#pragma unroll
      for (int jj = 0; jj < 4; jj++)
        lpart[lb + (wave * 2 + rg) * 16 + quad * 4 + jj] = l_r[rg][jj];
  }
}

// ---------------------------------------------------------------- linv_k
// linv[bh*2048+n] = 1/(l0+l1)
__global__ __launch_bounds__(256) void linv_k(const float* __restrict__ lpart,
                                              float* __restrict__ linv) {
  int i = blockIdx.x * 256 + threadIdx.x;  // 0..32767
  linv[i] = 1.f / (lpart[i] + lpart[32768 + i]);
}

// ---------------------------------------------------------------- out_gemm
// Fused merge + projection: A-staging sums the 2 split-K partials and
// normalizes by linv, writing packed frag tiles into LDS directly.
// Mapping = composition of merge's verified G-decomposition with the
// R5 out_gemm staging: for (c,mtb,mf,ks,qd,l2): t=(mtb*8+mf)*16+l2,
// bh=(t>>11)*8+(ks>>1), n=t&2047, src=(bh*2048+n)*192+c*64+(ks&1)*32+qd*8.
__global__ __launch_bounds__(256, 2) void out_gemm(const short* __restrict__ opart,
                                                   const float* __restrict__ linv,
                                                   const short* __restrict__ wop,
                                                   float* __restrict__ out) {
  __shared__ __align__(16) short Al[4096], Bl[2048];
  int c = blockIdx.z, ntb = blockIdx.x, mtb = blockIdx.y;
  int tid = threadIdx.x, wave = tid >> 6, lane = tid & 63;
  int ln = lane & 15, quad = lane >> 4;
  int wm = wave >> 1, wn = wave & 1;
  const size_t HSTR = (size_t)16 * 2048 * 192;

  f32x4 acc[4][2] = {};
  const short* gBb = wop + ((size_t)(ntb * 4) * 16) * 512;
  for (int ks = 0; ks < 16; ks++) {
#pragma unroll
    for (int ch = 0; ch < 2; ch++) {
      int gi = ch * 256 + tid;            // mf(3b) | qd(2b) | l2(4b)
      int mf = gi >> 6, qd = (gi >> 4) & 3, l2 = gi & 15;
      int t = (mtb * 8 + mf) * 16 + l2;
      int bh = (t >> 11) * 8 + (ks >> 1), n = t & 2047;
      size_t base = ((size_t)bh * 2048 + n) * 192 + c * 64 + (ks & 1) * 32 + qd * 8;
      bf16x8 o0 = *(const bf16x8*)(opart + base);
      bf16x8 o1 = *(const bf16x8*)(opart + HSTR + base);
      float iv = linv[bh * 2048 + n];
      bf16x8 r;
#pragma unroll
      for (int j = 0; j < 8; j++) {
        union { unsigned u; float f; } a, b;
        a.u = ((unsigned)(unsigned short)o0[j]) << 16;
        b.u = ((unsigned)(unsigned short)o1[j]) << 16;
        r[j] = f2bf((a.f + b.f) * iv);
      }
      *(bf16x8*)&Al[mf * 512 + (qd * 16 + l2) * 8] = r;
    }
    {
      int nf2 = tid >> 6;
      load_lds16(gBb + (size_t)(nf2 * 16 + ks) * 512 + lane * 8, &Bl[tid * 8]);
    }
    __syncthreads();
    bf16x8 af[4], bfr[2];
#pragma unroll
    for (int i = 0; i < 4; i++) af[i] = *(const bf16x8*)&Al[(wm * 4 + i) * 512 + lane * 8];
#pragma unroll
    for (int j = 0; j < 2; j++) bfr[j] = *(const bf16x8*)&Bl[(wn * 2 + j) * 512 + lane * 8];
#pragma unroll
    for (int i = 0; i < 4; i++)
#pragma unroll
      for (int j = 0; j < 2; j++)
        acc[i][j] = __builtin_amdgcn_mfma_f32_16x16x32_bf16(af[i], bfr[j], acc[i][j], 0, 0, 0);
    __syncthreads();
  }
#pragma unroll
  for (int i = 0; i < 4; i++) {
#pragma unroll
    for (int j = 0; j < 2; j++) {
      int o2 = ntb * 64 + (wn * 2 + j) * 16 + ln;
#pragma unroll
      for (int jj = 0; jj < 4; jj++) {
        int t = mtb * 128 + (wm * 4 + i) * 16 + quad * 4 + jj;
        out[((size_t)t * 256 + o2) * 3 + c] = acc[i][j][jj];
      }
    }
  }
}

// ---------------------------------------------------------------- launch
extern "C" void kernel_launch(void* const* d_in, const int* in_sizes, int n_in,
                              void* d_out, int out_size, void* d_ws, size_t ws_size,
                              hipStream_t stream) {
  const float* x  = (const float*)d_in[0];
  const float* Wq = (const float*)d_in[1];
  const float* Wk = (const float*)d_in[2];
  const float* Wv = (const float*)d_in[3];
  const float* Wo = (const float*)d_in[4];
  float* out = (float*)d_out;

  // R5-exact workspace layout (83,099,648 B total)
  short* ws    = (short*)d_ws;
  short* xcp   = ws;                                   // 3*4096*256
  short* wqkvp = xcp + 3 * NTOK * CIN;                 // 1536*256
  short* wop   = wqkvp + 1536 * 256;                   // 256*512
  short* qp    = wop + 256 * 512;                      // 16*2048*192
  short* kp    = qp + (size_t)BHTOT * NSEQ * E;
  short* vp    = kp + (size_t)BHTOT * NSEQ * E;
  short* spare = vp + (size_t)BHTOT * NSEQ * E;        // old owp slot (3*4096*512)
  short* opart = spare + (size_t)3 * NTOK * DINNER;    // 2*16*2048*192
  float* lpart = (float*)(opart + (size_t)2 * BHTOT * NSEQ * E);  // 2*16*2048 fp32
  float* linv  = (float*)spare;                        // 16*2048 fp32 (in spare slot)

  prep_w<<<2048, 256, 0, stream>>>(Wq, Wk, Wv, Wo, wqkvp, wop);
  prep_x<<<NTOK * CIN / 256, 256, 0, stream>>>(x, xcp);
  qkv_gemm<<<dim3(12, 32, 3), 256, 0, stream>>>(xcp, wqkvp, qp, kp, vp);
  attn<<<dim3(32, 16), 256, 0, stream>>>(qp, kp, vp, opart, lpart);
  linv_k<<<128, 256, 0, stream>>>(lpart, linv);
  out_gemm<<<dim3(4, 32, 3), 256, 0, stream>>>(opart, linv, wop, out);
}